// Round 5
// baseline (189.068 us; speedup 1.0000x reference)
//
#include <hip/hip_runtime.h>
#include <stdint.h>

using u16 = unsigned short;
typedef __attribute__((ext_vector_type(8))) _Float16 half8;
typedef __attribute__((ext_vector_type(4))) float f32x4;
typedef __attribute__((ext_vector_type(4))) unsigned short u16x4;

#define S_LEN 2048
#define D_MODEL 1024
#define NHEAD 16
#define HDIM 64

__device__ __forceinline__ u16 f2h_bits(float f){
    _Float16 h = (_Float16)f;
    return __builtin_bit_cast(u16, h);
}

typedef __attribute__((address_space(1))) void gvoid;
typedef __attribute__((address_space(3))) void lvoid;
__device__ __forceinline__ void gload_lds16(const u16* g, u16* l){
    __builtin_amdgcn_global_load_lds((gvoid*)(uintptr_t)g, (lvoid*)l, 16, 0, 0);
}

// ---------- x fp32 -> fp16 ----------
__global__ __launch_bounds__(256) void k_cvt_x(const float* __restrict__ x, u16* __restrict__ xh){
    int i = blockIdx.x*256 + threadIdx.x;
    float4 v = reinterpret_cast<const float4*>(x)[i];
    u16x4 o;
    o.x = f2h_bits(v.x); o.y = f2h_bits(v.y); o.z = f2h_bits(v.z); o.w = f2h_bits(v.w);
    reinterpret_cast<u16x4*>(xh)[i] = o;
}

// ---------- W [K][N] fp32 -> WT [N][K] fp16 (transpose via LDS) ----------
__global__ __launch_bounds__(256) void k_cvt_wT(const float* __restrict__ W, u16* __restrict__ WT,
                                                int K, int N){
    __shared__ float t[32][33];
    int tx = threadIdx.x & 31, ty = threadIdx.x >> 5;   // 32 x 8
    int n0 = blockIdx.x*32, k0 = blockIdx.y*32;
    #pragma unroll
    for (int i=0;i<4;++i) t[ty+8*i][tx] = W[(size_t)(k0+ty+8*i)*N + n0+tx];
    __syncthreads();
    #pragma unroll
    for (int i=0;i<4;++i) WT[(size_t)(n0+ty+8*i)*K + k0+tx] = f2h_bits(t[tx][ty+8*i]);
}

// ---------- GEMM (m97 structure): 128x128 tile, BK=32, LDS-staged via global_load_lds ----------
template<int EPI>
__global__ __launch_bounds__(256) void k_gemm(const u16* __restrict__ A, const u16* __restrict__ BT,
                                              float* __restrict__ Cf, u16* __restrict__ Qh,
                                              u16* __restrict__ Kh, u16* __restrict__ Vt){
    constexpr int Kd = 1024;
    __shared__ u16 As[128*32];
    __shared__ u16 Bs[128*32];
    int nwg = gridDim.x;
    int cpx = nwg >> 3;
    int wg  = ((int)blockIdx.x & 7)*cpx + ((int)blockIdx.x >> 3);   // XCD-chunked
    int tm = wg & 31, tn = wg >> 5;                                 // m-fastest within chunk
    int t = threadIdx.x;
    int w = t >> 6, lane = t & 63;
    int lr = lane & 15, lg = lane >> 4;
    int wm = (w>>1)*64, wn = (w&1)*64;
    int m0 = tm*128 + wm, n0 = tn*128 + wn;

    const u16* aG = A  + (size_t)(tm*128 + (t>>2))*Kd + (t&3)*8;
    const u16* bG = BT + (size_t)(tn*128 + (t>>2))*Kd + (t&3)*8;
    u16* aL = As + (t>>2)*32 + (t&3)*8;
    u16* bL = Bs + (t>>2)*32 + (t&3)*8;

    f32x4 acc[4][4];
    #pragma unroll
    for (int i=0;i<4;++i)
        #pragma unroll
        for (int j=0;j<4;++j) acc[i][j] = (f32x4){0.f,0.f,0.f,0.f};

    for (int kk=0; kk<Kd; kk+=32){
        gload_lds16(aG + kk, aL);
        gload_lds16(aG + kk + (size_t)64*Kd, aL + 64*32);
        gload_lds16(bG + kk, bL);
        gload_lds16(bG + kk + (size_t)64*Kd, bL + 64*32);
        __syncthreads();

        half8 av[4], bv[4];
        #pragma unroll
        for (int mf=0;mf<4;++mf) av[mf] = *reinterpret_cast<const half8*>(&As[(wm+mf*16+lr)*32 + lg*8]);
        #pragma unroll
        for (int nf=0;nf<4;++nf) bv[nf] = *reinterpret_cast<const half8*>(&Bs[(wn+nf*16+lr)*32 + lg*8]);
        __builtin_amdgcn_s_setprio(1);
        #pragma unroll
        for (int mf=0;mf<4;++mf)
            #pragma unroll
            for (int nf=0;nf<4;++nf)
                acc[mf][nf] = __builtin_amdgcn_mfma_f32_16x16x32_f16(av[mf], bv[nf], acc[mf][nf], 0,0,0);
        __builtin_amdgcn_s_setprio(0);
        __syncthreads();
    }

    if (EPI == 0){
        #pragma unroll
        for (int mf=0;mf<4;++mf)
            #pragma unroll
            for (int nf=0;nf<4;++nf)
                #pragma unroll
                for (int j=0;j<4;++j)
                    Cf[(size_t)(m0+mf*16+lg*4+j)*D_MODEL + n0+nf*16+lr] = acc[mf][nf][j];
    } else {
        #pragma unroll
        for (int mf=0;mf<4;++mf){
            int r0 = m0 + mf*16 + lg*4;
            int b  = r0 >> 11, s = r0 & 2047;
            #pragma unroll
            for (int nf=0;nf<4;++nf){
                int col = n0 + nf*16 + lr;
                int which = col >> 10;
                int d  = col & 1023;
                int h  = d >> 6, di = d & 63;
                int bh = b*NHEAD + h;
                if (which == 2){
                    u16x4 pv;
                    pv.x = f2h_bits(acc[mf][nf][0]);
                    pv.y = f2h_bits(acc[mf][nf][1]);
                    pv.z = f2h_bits(acc[mf][nf][2]);
                    pv.w = f2h_bits(acc[mf][nf][3]);
                    *reinterpret_cast<u16x4*>(Vt + ((size_t)bh*HDIM + di)*S_LEN + s) = pv;
                } else {
                    u16* dst = (which==0 ? Qh : Kh) + ((size_t)bh*S_LEN + s)*HDIM + di;
                    #pragma unroll
                    for (int j=0;j<4;++j) dst[(size_t)j*HDIM] = f2h_bits(acc[mf][nf][j]);
                }
            }
        }
    }
}

// ---------- flash attention v4: split-K, 4 cooperating waves per q-tile ----------
// Block = 256 thr = 4 waves on ONE 32-row q-tile; wave w does k-tiles kt = w, w+4, ...
// Each wave runs an independent online softmax over its subset; LDS combine at end:
//   m* = max_w m_w;  O* = sum_w O_w * 2^(m_w-m*);  l* = sum_w l_w * 2^(m_w-m*).
// No barriers in the k-loop (trip counts differ per wave); exactly 2 barriers after.
// LDS: plds[4 waves][32][72] (18432B) during loop, REUSED as Of[4][32][68]+m/l (35840B)
// for the combine (temporally disjoint, barrier-separated). 4 blocks/CU -> 16 waves/CU.
__global__ __launch_bounds__(256,4) void k_attn(const u16* __restrict__ Q, const u16* __restrict__ K,
                                                const u16* __restrict__ Vt, u16* __restrict__ Mg){
    __shared__ __align__(16) char smem[35840];
    int t = threadIdx.x;
    int w = t >> 6, lane = t & 63;
    int lr = lane & 15, lg = lane >> 4;
    int blk = blockIdx.x;
    int bh  = blk & 31;                          // XCD = blk%8 clusters K/V in L2
    int qt  = 63 - (blk >> 5);                   // heavy q-tiles first
    int q0  = qt*32;
    int b = bh >> 4, h = bh & 15;
    const u16* Qp = Q  + (size_t)bh*S_LEN*HDIM;
    const u16* Kp = K  + (size_t)bh*S_LEN*HDIM;
    const u16* Vp = Vt + (size_t)bh*HDIM*S_LEN;
    u16 (*pw)[72] = reinterpret_cast<u16(*)[72]>(smem) + w*32;   // this wave's P tile

    // Q fragments (B-operand), pre-scaled by log2(e)
    half8 qf[2][2];
    #pragma unroll
    for (int qi=0;qi<2;++qi)
        #pragma unroll
        for (int ks=0;ks<2;++ks){
            half8 v = *reinterpret_cast<const half8*>(Qp + (size_t)(q0+qi*16+lr)*HDIM + ks*32 + lg*8);
            #pragma unroll
            for (int j=0;j<8;++j) v[j] = v[j] * (_Float16)1.44269504f;
            qf[qi][ks] = v;
        }

    f32x4 oacc[2][4];
    float mrow[2], lrow[2];
    #pragma unroll
    for (int mf=0;mf<2;++mf){
        #pragma unroll
        for (int nf=0;nf<4;++nf) oacc[mf][nf] = (f32x4){0.f,0.f,0.f,0.f};
        mrow[mf] = -1e30f; lrow[mf] = 0.f;
    }

    int ktiles = (q0 + 32 + 63) >> 6;
    for (int kt=w; kt<ktiles; kt+=4){
        int kbase = kt*64;
        half8 kfr[4][2];
        #pragma unroll
        for (int kf=0;kf<4;++kf)
            #pragma unroll
            for (int ks=0;ks<2;++ks)
                kfr[kf][ks] = *reinterpret_cast<const half8*>(Kp + (size_t)(kbase+kf*16+lr)*HDIM + ks*32 + lg*8);
        f32x4 sc[4][2];
        #pragma unroll
        for (int kf=0;kf<4;++kf)
            #pragma unroll
            for (int qi=0;qi<2;++qi) sc[kf][qi] = (f32x4){0.f,0.f,0.f,0.f};
        __builtin_amdgcn_s_setprio(1);
        #pragma unroll
        for (int kf=0;kf<4;++kf)
            #pragma unroll
            for (int qi=0;qi<2;++qi)
                #pragma unroll
                for (int ks=0;ks<2;++ks)
                    sc[kf][qi] = __builtin_amdgcn_mfma_f32_16x16x32_f16(kfr[kf][ks], qf[qi][ks], sc[kf][qi], 0,0,0);
        __builtin_amdgcn_s_setprio(0);

        half8 vf[4][2];
        #pragma unroll
        for (int nf=0;nf<4;++nf)
            #pragma unroll
            for (int kh=0;kh<2;++kh)
                vf[nf][kh] = *reinterpret_cast<const half8*>(Vp + (size_t)(nf*16+lr)*S_LEN + kbase + kh*32 + lg*8);

        if (kt == ktiles-1){                     // only the last tile crosses the diagonal
            #pragma unroll
            for (int kf=0;kf<4;++kf)
                #pragma unroll
                for (int qi=0;qi<2;++qi)
                    #pragma unroll
                    for (int j=0;j<4;++j)
                        if (kbase+kf*16+lg*4+j > q0+qi*16+lr) sc[kf][qi][j] = -1e9f;
        }

        float pmax[2];
        #pragma unroll
        for (int qi=0;qi<2;++qi){
            float t0 = fmaxf(fmaxf(sc[0][qi][0], sc[0][qi][1]), fmaxf(sc[0][qi][2], sc[0][qi][3]));
            float t1 = fmaxf(fmaxf(sc[1][qi][0], sc[1][qi][1]), fmaxf(sc[1][qi][2], sc[1][qi][3]));
            float t2 = fmaxf(fmaxf(sc[2][qi][0], sc[2][qi][1]), fmaxf(sc[2][qi][2], sc[2][qi][3]));
            float t3 = fmaxf(fmaxf(sc[3][qi][0], sc[3][qi][1]), fmaxf(sc[3][qi][2], sc[3][qi][3]));
            float tm = fmaxf(fmaxf(t0,t1), fmaxf(t2,t3));
            tm = fmaxf(tm, __shfl_xor(tm,16));
            tm = fmaxf(tm, __shfl_xor(tm,32));
            pmax[qi] = tm;
        }
        bool need = (pmax[0] > mrow[0]+8.0f) || (pmax[1] > mrow[1]+8.0f);
        if (__any(need)){
            float aq[2];
            #pragma unroll
            for (int qi=0;qi<2;++qi){
                float mnew = fmaxf(mrow[qi], pmax[qi]);
                aq[qi] = __builtin_amdgcn_exp2f(mrow[qi] - mnew);
                mrow[qi] = mnew;
                lrow[qi] *= aq[qi];
            }
            float am[2][4];
            #pragma unroll
            for (int mf=0;mf<2;++mf)
                #pragma unroll
                for (int j=0;j<4;++j) am[mf][j] = __shfl(aq[mf], lg*4+j);
            #pragma unroll
            for (int mf=0;mf<2;++mf)
                #pragma unroll
                for (int nf=0;nf<4;++nf)
                    #pragma unroll
                    for (int j=0;j<4;++j) oacc[mf][nf][j] *= am[mf][j];
        }
        #pragma unroll
        for (int qi=0;qi<2;++qi){
            float m = mrow[qi];
            float rs = 0.f;
            #pragma unroll
            for (int kf=0;kf<4;++kf){
                #pragma unroll
                for (int j=0;j<4;++j){
                    float e = __builtin_amdgcn_exp2f(sc[kf][qi][j] - m);
                    sc[kf][qi][j] = e;
                    rs += e;
                }
            }
            rs += __shfl_xor(rs,16);
            rs += __shfl_xor(rs,32);
            lrow[qi] += rs;
        }
        #pragma unroll
        for (int kf=0;kf<4;++kf)
            #pragma unroll
            for (int qi=0;qi<2;++qi){
                u16x4 pk;
                pk.x = f2h_bits(sc[kf][qi][0]);
                pk.y = f2h_bits(sc[kf][qi][1]);
                pk.z = f2h_bits(sc[kf][qi][2]);
                pk.w = f2h_bits(sc[kf][qi][3]);
                *reinterpret_cast<u16x4*>(&pw[qi*16+lr][kf*16+lg*4]) = pk;
            }
        asm volatile("s_waitcnt lgkmcnt(0)" ::: "memory");
        __builtin_amdgcn_sched_barrier(0);

        half8 pa[2][2];
        #pragma unroll
        for (int mf=0;mf<2;++mf)
            #pragma unroll
            for (int kh=0;kh<2;++kh)
                pa[mf][kh] = *reinterpret_cast<const half8*>(&pw[mf*16+lr][kh*32 + lg*8]);
        __builtin_amdgcn_s_setprio(1);
        #pragma unroll
        for (int mf=0;mf<2;++mf)
            #pragma unroll
            for (int nf=0;nf<4;++nf)
                #pragma unroll
                for (int kh=0;kh<2;++kh)
                    oacc[mf][nf] = __builtin_amdgcn_mfma_f32_16x16x32_f16(pa[mf][kh], vf[nf][kh], oacc[mf][nf], 0,0,0);
        __builtin_amdgcn_s_setprio(0);
    }

    // ---- combine: all waves' plds use done before Of overwrites (aliased LDS) ----
    __syncthreads();
    float* Of  = reinterpret_cast<float*>(smem);           // [4][32][68]
    float* mls = reinterpret_cast<float*>(smem + 34816);   // [4][32]
    float* lls = reinterpret_cast<float*>(smem + 34816 + 512);
    #pragma unroll
    for (int mf=0;mf<2;++mf)
        #pragma unroll
        for (int nf=0;nf<4;++nf)
            #pragma unroll
            for (int j=0;j<4;++j)
                Of[(w*32 + mf*16+lg*4+j)*68 + nf*16+lr] = oacc[mf][nf][j];
    #pragma unroll
    for (int qi=0;qi<2;++qi){
        mls[w*32 + qi*16+lr] = mrow[qi];       // lg duplicates write same value (benign)
        lls[w*32 + qi*16+lr] = lrow[qi];
    }
    __syncthreads();
    // wave w merges rows [8w, 8w+8), lane = column
    int c = lane;
    #pragma unroll
    for (int r8=0;r8<8;++r8){
        int r = w*8 + r8;
        float m0=mls[r], m1=mls[32+r], m2=mls[64+r], m3=mls[96+r];
        float mM = fmaxf(fmaxf(m0,m1), fmaxf(m2,m3));
        float s0 = __builtin_amdgcn_exp2f(m0-mM);
        float s1 = __builtin_amdgcn_exp2f(m1-mM);
        float s2 = __builtin_amdgcn_exp2f(m2-mM);
        float s3 = __builtin_amdgcn_exp2f(m3-mM);
        float l  = lls[r]*s0 + lls[32+r]*s1 + lls[64+r]*s2 + lls[96+r]*s3;
        float o  = Of[(     r)*68+c]*s0 + Of[( 32+r)*68+c]*s1
                 + Of[( 64+r)*68+c]*s2 + Of[( 96+r)*68+c]*s3;
        Mg[(size_t)(b*S_LEN + q0 + r)*D_MODEL + h*HDIM + c] = f2h_bits(o / l);
    }
}

extern "C" void kernel_launch(void* const* d_in, const int* in_sizes, int n_in,
                              void* d_out, int out_size, void* d_ws, size_t ws_size,
                              hipStream_t stream) {
    const float* x    = (const float*)d_in[0];
    const float* wqkv = (const float*)d_in[1];
    const float* wout = (const float*)d_in[2];
    float* out = (float*)d_out;
    char* ws = (char*)d_ws;

    const size_t MB = 1u<<20;
    u16* xh     = (u16*)(ws + 0*MB);
    u16* wqkvT  = (u16*)(ws + 8*MB);
    u16* woutT  = (u16*)(ws + 14*MB);
    u16* Qh     = (u16*)(ws + 16*MB);
    u16* Kh     = (u16*)(ws + 24*MB);
    u16* Vt     = (u16*)(ws + 32*MB);
    u16* Mg     = (u16*)(ws + 40*MB);

    k_cvt_x <<<4096, 256, 0, stream>>>(x, xh);
    k_cvt_wT<<<dim3(96,32), 256, 0, stream>>>(wqkv, wqkvT, 1024, 3072);
    k_cvt_wT<<<dim3(32,32), 256, 0, stream>>>(wout, woutT, 1024, 1024);
    k_gemm<1><<<768, 256, 0, stream>>>(xh, wqkvT, nullptr, Qh, Kh, Vt);
    k_attn  <<<2048, 256, 0, stream>>>(Qh, Kh, Vt, Mg);
    k_gemm<0><<<256, 256, 0, stream>>>(Mg, woutT, out, nullptr, nullptr, nullptr);
}